// Round 7
// baseline (166.648 us; speedup 1.0000x reference)
//
#include <hip/hip_runtime.h>
#include <math.h>

// SMEFTNet forward. B=128, N=128, H=16.  Two kernels.
// Block = 16 nodes, 512 threads = 8 waves. Wave w<4 ("primary") and w+4
// ("secondary") each process j-half (0/1) for nodes (w&3)*4..+4.
// lane = g*16+t: g = node subgroup, t = channel & j-sub-index.
// Secondary writes A-partials to LDS; one barrier; primary merges, does the
// 16-lane DPP reduce + bpermute broadcast, 2nd MLP layer (w1^T staged in
// LDS), rotation, and epilogue (conv0: proj u1/v1; conv1: readout partials).
// conv1's last-finishing block per batch (atomic counter) runs the final
// readout MLP inline -> no third kernel.

#define BB 128
#define NN 128
#define BN (BB * NN)

typedef float f32x2 __attribute__((ext_vector_type(2)));

__device__ __forceinline__ f32x2 pk2(float s) { f32x2 r; r[0] = s; r[1] = s; return r; }
__device__ __forceinline__ f32x2 pkfma(f32x2 a, f32x2 b, f32x2 c) {
    return __builtin_elementwise_fma(a, b, c);
}
__device__ __forceinline__ f32x2 pkmax(f32x2 a, f32x2 b) {
    return __builtin_elementwise_max(a, b);
}

template <int CTRL>
__device__ __forceinline__ float dpp_add(float x) {
    int tmp = __builtin_amdgcn_update_dpp(0, __float_as_int(x), CTRL, 0xF, 0xF, true);
    return x + __int_as_float(tmp);
}

// Sum within each 16-lane row; result valid in lane (l|15) of each row.
__device__ __forceinline__ float grp16_sum(float x) {
    x = dpp_add<0xB1>(x);   // quad_perm [1,0,3,2]
    x = dpp_add<0x4E>(x);   // quad_perm [2,3,0,1]
    x = dpp_add<0x114>(x);  // row_shr:4
    x = dpp_add<0x118>(x);  // row_shr:8
    return x;
}

__device__ __forceinline__ float bcast_grp(float x, int bidx) {
    return __int_as_float(__builtin_amdgcn_ds_bpermute(bidx, __float_as_int(x)));
}

// packed group sum + broadcast: every lane gets its group's channel-pair sum
__device__ __forceinline__ f32x2 grp16_red2(f32x2 x, int bidx) {
    f32x2 r;
    r[0] = bcast_grp(grp16_sum(x[0]), bidx);
    r[1] = bcast_grp(grp16_sum(x[1]), bidx);
    return r;
}

// ---------------- K1: conv0 + fused proj for conv1 ----------------
__global__ __launch_bounds__(512, 4) void conv0_kernel(
    const float* __restrict__ ang,   // (B,N,2)
    const float* __restrict__ w0,    // c0_w0 (5,16)
    const float* __restrict__ b0,    // (16)
    const float* __restrict__ w1,    // c0_w1 (16,17)
    const float* __restrict__ b1,    // (17)
    const float* __restrict__ nw0,   // c1_w0 (50,16)
    const float* __restrict__ nb0,   // c1_b0 (16)
    float* __restrict__ rec,         // (BN,4): re,im,ex,ey (post-rotation)
    float* __restrict__ u1,          // (BN,16)
    float* __restrict__ v1,          // (BN,16)
    int* __restrict__ counter)       // (B)
{
    const int tid   = threadIdx.x;
    const int lane  = tid & 63;
    const int wid   = tid >> 6;
    const int t     = lane & 15;
    const int g     = lane >> 4;
    const int wpair = wid & 3;
    const int jhalf = wid >> 2;
    const int ni    = blockIdx.x * 16 + wpair * 4 + g;
    const int base  = (blockIdx.x >> 3) << 7;

    __shared__ float w1T[17][20];
    __shared__ float wkT[32][20];
    __shared__ float Ap[4][17][64];
    __shared__ float hls[16][20];

    if (tid == 0 && (blockIdx.x & 7) == 0) counter[blockIdx.x >> 3] = 0;

    // stage w1^T and combined proj weights
    if (tid < 272) w1T[tid % 17][tid / 17] = w1[tid];
    {
        const int o = tid >> 4, c = tid & 15, k_ = o & 15;
        const float a_ = nw0[(o < 16 ? 0 : 256) + c * 16 + k_];
        const float c_ = nw0[512 + c * 16 + k_];
        wkT[o][c] = (o < 16) ? (a_ - c_) : (a_ + c_);
    }

    // my node
    const float2 ai = ((const float2*)ang)[ni];
    const float r2i = fmaf(ai.x, ai.x, ai.y * ai.y);
    const float abszi = __builtin_amdgcn_sqrtf(r2i);
    const float ivi = fminf(__builtin_amdgcn_rsqf(r2i), 1e12f);
    const float eix = ai.x * ivi, eiy = ai.y * ivi;

    // layer-0 constants: u0b per-lane; q0/wc/ws wave-uniform (s_load)
    f32x2 u0b2[8], q02[8], wc2[8], ws2[8];
    #pragma unroll
    for (int p = 0; p < 8; ++p) {
        f32x2 wa  = *(const f32x2*)(w0 + 2 * p);
        f32x2 wb  = *(const f32x2*)(w0 + 16 + 2 * p);
        f32x2 wcv = *(const f32x2*)(w0 + 32 + 2 * p);
        f32x2 bb  = *(const f32x2*)(b0 + 2 * p);
        u0b2[p] = pkfma(pk2(abszi), wa - wcv, bb);
        q02[p]  = wb + wcv;
        wc2[p]  = *(const f32x2*)(w0 + 48 + 2 * p);
        ws2[p]  = *(const f32x2*)(w0 + 64 + 2 * p);
    }

    f32x2 A2[8];
    #pragma unroll
    for (int p = 0; p < 8; ++p) A2[p] = pk2(0.0f);
    float degf = 0.0f;

    #pragma unroll
    for (int jj = 0; jj < 4; ++jj) {
        const float2 aj = ((const float2*)ang)[base + jhalf * 64 + jj * 16 + t];
        const float r2j = fmaf(aj.x, aj.x, aj.y * aj.y);
        const float abszj = __builtin_amdgcn_sqrtf(r2j);
        const float ivj = fminf(__builtin_amdgcn_rsqf(r2j), 1e12f);
        const float ejx = aj.x * ivj, ejy = aj.y * ivj;
        const float dre = ai.x - aj.x, dim = ai.y - aj.y;
        const float d2 = fmaf(dre, dre, dim * dim);
        const float adjf = (d2 <= 0.16f) ? 1.0f : 0.0f;
        degf += adjf;
        const f32x2 cos2 = pk2(fmaf(eix, ejx, eiy * ejy));
        const f32x2 sin2 = pk2(fmaf(eiy, ejx, -(eix * ejy)));
        const f32x2 ab2 = pk2(abszj);
        const f32x2 adj2 = pk2(adjf);
        #pragma unroll
        for (int p = 0; p < 8; ++p) {
            f32x2 z = pkfma(ab2, q02[p], u0b2[p]);
            z = pkfma(cos2, wc2[p], z);
            z = pkfma(sin2, ws2[p], z);
            f32x2 a = pkmax(z, z * 0.01f);
            A2[p] = pkfma(a, adj2, A2[p]);
        }
    }

    if (jhalf == 1) {  // secondary: deposit partials
        #pragma unroll
        for (int p = 0; p < 8; ++p) {
            Ap[wpair][2 * p][lane]     = A2[p][0];
            Ap[wpair][2 * p + 1][lane] = A2[p][1];
        }
        Ap[wpair][16][lane] = degf;
    }
    __syncthreads();
    if (jhalf == 1) return;

    // primary: merge + reduce
    #pragma unroll
    for (int p = 0; p < 8; ++p) {
        A2[p][0] += Ap[wpair][2 * p][lane];
        A2[p][1] += Ap[wpair][2 * p + 1][lane];
    }
    degf += Ap[wpair][16][lane];

    const int bidx = (lane | 15) << 2;
    f32x2 Ak2[8];
    #pragma unroll
    for (int p = 0; p < 8; ++p) Ak2[p] = grp16_red2(A2[p], bidx);
    const float invdeg = __builtin_amdgcn_rcpf(bcast_grp(grp16_sum(degf), bidx));

    // 2nd layer: channel t (w1^T row from LDS) + gamma (uniform col, s_load)
    f32x2 s2 = pk2(0.0f), g2 = pk2(0.0f);
    {
        const float4* wr = (const float4*)&w1T[t][0];
        float4 r0 = wr[0], r1 = wr[1], r2 = wr[2], r3 = wr[3];
        f32x2 w1r[8];
        w1r[0][0] = r0.x; w1r[0][1] = r0.y; w1r[1][0] = r0.z; w1r[1][1] = r0.w;
        w1r[2][0] = r1.x; w1r[2][1] = r1.y; w1r[3][0] = r1.z; w1r[3][1] = r1.w;
        w1r[4][0] = r2.x; w1r[4][1] = r2.y; w1r[5][0] = r2.z; w1r[5][1] = r2.w;
        w1r[6][0] = r3.x; w1r[6][1] = r3.y; w1r[7][0] = r3.z; w1r[7][1] = r3.w;
        #pragma unroll
        for (int p = 0; p < 8; ++p) {
            f32x2 wg; wg[0] = w1[(2 * p) * 17 + 16]; wg[1] = w1[(2 * p + 1) * 17 + 16];
            s2 = pkfma(Ak2[p], w1r[p], s2);
            g2 = pkfma(Ak2[p], wg, g2);
        }
    }
    const float mt    = fmaf(s2[0] + s2[1], invdeg, b1[t]);
    const float gamma = fmaf(g2[0] + g2[1], invdeg, b1[16]);

    // rotation (v_cos/v_sin take revolutions); rotate raw and unit vectors
    {
        const float gf = gamma - floorf(gamma);
        const float cs = __builtin_amdgcn_cosf(gf);
        const float sn = __builtin_amdgcn_sinf(gf);
        if (t == 0) {
            const float re2 = cs * ai.x - sn * ai.y;
            const float im2 = fmaf(sn, ai.x, cs * ai.y);
            const float e1x = cs * eix - sn * eiy;
            const float e1y = fmaf(sn, eix, cs * eiy);
            ((float4*)rec)[ni] = make_float4(re2, im2, e1x, e1y);
        }
    }

    hls[wpair * 4 + g][t] = mt;   // same-wave exchange (in-order, no barrier)

    // proj: 2 passes x 64 lanes = 4 nodes x (16 u + 16 v)
    const int o = lane & 31;
    const int kk = o & 15;
    const bool isU = (o < 16);
    const float accb = isU ? nb0[kk] : 0.0f;
    f32x2 wk2[8];
    {
        const float4* wr = (const float4*)&wkT[o][0];
        float4 r0 = wr[0], r1 = wr[1], r2 = wr[2], r3 = wr[3];
        wk2[0][0] = r0.x; wk2[0][1] = r0.y; wk2[1][0] = r0.z; wk2[1][1] = r0.w;
        wk2[2][0] = r1.x; wk2[2][1] = r1.y; wk2[3][0] = r1.z; wk2[3][1] = r1.w;
        wk2[4][0] = r2.x; wk2[4][1] = r2.y; wk2[5][0] = r2.z; wk2[5][1] = r2.w;
        wk2[6][0] = r3.x; wk2[6][1] = r3.y; wk2[7][0] = r3.z; wk2[7][1] = r3.w;
    }
    #pragma unroll
    for (int ps = 0; ps < 2; ++ps) {
        const int nl = (lane >> 5) + 2 * ps;
        const int node = wpair * 4 + nl;
        const float4* hr = (const float4*)&hls[node][0];
        float4 h0 = hr[0], h1 = hr[1], h2 = hr[2], h3 = hr[3];
        f32x2 hv[8];
        hv[0][0] = h0.x; hv[0][1] = h0.y; hv[1][0] = h0.z; hv[1][1] = h0.w;
        hv[2][0] = h1.x; hv[2][1] = h1.y; hv[3][0] = h1.z; hv[3][1] = h1.w;
        hv[4][0] = h2.x; hv[4][1] = h2.y; hv[5][0] = h2.z; hv[5][1] = h2.w;
        hv[6][0] = h3.x; hv[6][1] = h3.y; hv[7][0] = h3.z; hv[7][1] = h3.w;
        f32x2 acc2 = pk2(0.0f);
        #pragma unroll
        for (int p = 0; p < 8; ++p) acc2 = pkfma(hv[p], wk2[p], acc2);
        const float acc = acc2[0] + acc2[1] + accb;
        const int nout = blockIdx.x * 16 + node;
        if (isU) u1[nout * 16 + kk] = acc;
        else     v1[nout * 16 + kk] = acc;
    }
}

// ---------------- K2: conv1 + partials + last-block readout ----------------
__global__ __launch_bounds__(512, 4) void conv1_kernel(
    const float* __restrict__ pt,    // (B,N)
    const float* __restrict__ rec,   // (BN,4)
    const float* __restrict__ u1,    // (BN,16)
    const float* __restrict__ v1,    // (BN,16)
    const float* __restrict__ w0,    // c1_w0 (50,16)
    const float* __restrict__ w1,    // c1_w1 (16,17)
    const float* __restrict__ b1,    // (17)
    float* __restrict__ part,        // (4096,20)
    int* __restrict__ counter,       // (B)
    const float* __restrict__ rw0, const float* __restrict__ rb0,
    const float* __restrict__ rw1, const float* __restrict__ rb1,
    const float* __restrict__ rw2, const float* __restrict__ rb2,
    float* __restrict__ out)
{
    const int tid   = threadIdx.x;
    const int lane  = tid & 63;
    const int wid   = tid >> 6;
    const int t     = lane & 15;
    const int g     = lane >> 4;
    const int wpair = wid & 3;
    const int jhalf = wid >> 2;
    const int batch = blockIdx.x >> 3;
    const int ni    = blockIdx.x * 16 + wpair * 4 + g;
    const int base  = batch << 7;

    __shared__ float w1T[17][20];
    __shared__ float Ap[4][17][64];
    __shared__ float sbuf[20];
    __shared__ float xg[20];
    __shared__ float h1r[32];
    __shared__ int flag;

    if (tid < 272) w1T[tid % 17][tid / 17] = w1[tid];

    // my node
    const float4 r4i = ((const float4*)rec)[ni];
    const float rei = r4i.x, imi = r4i.y, eix = r4i.z, eiy = r4i.w;
    const float ptf = pt[ni];
    f32x2 u0b2[8];
    {
        const float4* ug = (const float4*)(u1 + (size_t)ni * 16);
        float4 q0 = ug[0], q1 = ug[1], q2 = ug[2], q3 = ug[3];
        u0b2[0][0] = q0.x; u0b2[0][1] = q0.y; u0b2[1][0] = q0.z; u0b2[1][1] = q0.w;
        u0b2[2][0] = q1.x; u0b2[2][1] = q1.y; u0b2[3][0] = q1.z; u0b2[3][1] = q1.w;
        u0b2[4][0] = q2.x; u0b2[4][1] = q2.y; u0b2[5][0] = q2.z; u0b2[5][1] = q2.w;
        u0b2[6][0] = q3.x; u0b2[6][1] = q3.y; u0b2[7][0] = q3.z; u0b2[7][1] = q3.w;
    }
    f32x2 wc2[8], ws2[8];
    #pragma unroll
    for (int p = 0; p < 8; ++p) {
        wc2[p] = *(const f32x2*)(w0 + 768 + 2 * p);
        ws2[p] = *(const f32x2*)(w0 + 784 + 2 * p);
    }

    f32x2 A2[8];
    #pragma unroll
    for (int p = 0; p < 8; ++p) A2[p] = pk2(0.0f);
    float degf = 0.0f;

    #pragma unroll
    for (int jj = 0; jj < 4; ++jj) {
        const int j = base + jhalf * 64 + jj * 16 + t;
        const float4 r4 = ((const float4*)rec)[j];
        f32x2 vj2[8];
        {
            const float4* vg = (const float4*)(v1 + (size_t)j * 16);
            float4 q0 = vg[0], q1 = vg[1], q2 = vg[2], q3 = vg[3];
            vj2[0][0] = q0.x; vj2[0][1] = q0.y; vj2[1][0] = q0.z; vj2[1][1] = q0.w;
            vj2[2][0] = q1.x; vj2[2][1] = q1.y; vj2[3][0] = q1.z; vj2[3][1] = q1.w;
            vj2[4][0] = q2.x; vj2[4][1] = q2.y; vj2[5][0] = q2.z; vj2[5][1] = q2.w;
            vj2[6][0] = q3.x; vj2[6][1] = q3.y; vj2[7][0] = q3.z; vj2[7][1] = q3.w;
        }
        const float dre = rei - r4.x, dim = imi - r4.y;
        const float d2 = fmaf(dre, dre, dim * dim);
        const float adjf = (d2 <= 0.16f) ? 1.0f : 0.0f;
        degf += adjf;
        const f32x2 cos2 = pk2(fmaf(eix, r4.z, eiy * r4.w));
        const f32x2 sin2 = pk2(fmaf(eiy, r4.z, -(eix * r4.w)));
        const f32x2 adj2 = pk2(adjf);
        #pragma unroll
        for (int p = 0; p < 8; ++p) {
            f32x2 z = u0b2[p] + vj2[p];
            z = pkfma(cos2, wc2[p], z);
            z = pkfma(sin2, ws2[p], z);
            f32x2 a = pkmax(z, z * 0.01f);
            A2[p] = pkfma(a, adj2, A2[p]);
        }
    }

    if (jhalf == 1) {
        #pragma unroll
        for (int p = 0; p < 8; ++p) {
            Ap[wpair][2 * p][lane]     = A2[p][0];
            Ap[wpair][2 * p + 1][lane] = A2[p][1];
        }
        Ap[wpair][16][lane] = degf;
    }
    __syncthreads();

    if (jhalf == 0) {
        #pragma unroll
        for (int p = 0; p < 8; ++p) {
            A2[p][0] += Ap[wpair][2 * p][lane];
            A2[p][1] += Ap[wpair][2 * p + 1][lane];
        }
        degf += Ap[wpair][16][lane];

        const int bidx = (lane | 15) << 2;
        f32x2 Ak2[8];
        #pragma unroll
        for (int p = 0; p < 8; ++p) Ak2[p] = grp16_red2(A2[p], bidx);
        const float invdeg = __builtin_amdgcn_rcpf(bcast_grp(grp16_sum(degf), bidx));

        f32x2 s2 = pk2(0.0f), g2 = pk2(0.0f);
        {
            const float4* wr = (const float4*)&w1T[t][0];
            float4 r0 = wr[0], r1 = wr[1], r2 = wr[2], r3 = wr[3];
            f32x2 w1r[8];
            w1r[0][0] = r0.x; w1r[0][1] = r0.y; w1r[1][0] = r0.z; w1r[1][1] = r0.w;
            w1r[2][0] = r1.x; w1r[2][1] = r1.y; w1r[3][0] = r1.z; w1r[3][1] = r1.w;
            w1r[4][0] = r2.x; w1r[4][1] = r2.y; w1r[5][0] = r2.z; w1r[5][1] = r2.w;
            w1r[6][0] = r3.x; w1r[6][1] = r3.y; w1r[7][0] = r3.z; w1r[7][1] = r3.w;
            #pragma unroll
            for (int p = 0; p < 8; ++p) {
                f32x2 wg; wg[0] = w1[(2 * p) * 17 + 16]; wg[1] = w1[(2 * p + 1) * 17 + 16];
                s2 = pkfma(Ak2[p], w1r[p], s2);
                g2 = pkfma(Ak2[p], wg, g2);
            }
        }
        const float mt    = fmaf(s2[0] + s2[1], invdeg, b1[t]);
        const float gamma = fmaf(g2[0] + g2[1], invdeg, b1[16]);

        const float gf = gamma - floorf(gamma);
        const float cs = __builtin_amdgcn_cosf(gf);
        const float sn = __builtin_amdgcn_sinf(gf);
        const float re2 = cs * rei - sn * imi;
        const float im2 = fmaf(sn, rei, cs * imi);

        // per-wave partials over its 4 nodes: xor16 + xor32
        float pm  = ptf * mt;
        float pre = ptf * re2;
        float pim = ptf * im2;
        float ppt = ptf;
        pm  += __int_as_float(__builtin_amdgcn_ds_swizzle(__float_as_int(pm),  0x401F));
        pre += __int_as_float(__builtin_amdgcn_ds_swizzle(__float_as_int(pre), 0x401F));
        pim += __int_as_float(__builtin_amdgcn_ds_swizzle(__float_as_int(pim), 0x401F));
        ppt += __int_as_float(__builtin_amdgcn_ds_swizzle(__float_as_int(ppt), 0x401F));
        pm  += __shfl_xor(pm, 32);
        pre += __shfl_xor(pre, 32);
        pim += __shfl_xor(pim, 32);
        ppt += __shfl_xor(ppt, 32);

        float* po = part + (size_t)(blockIdx.x * 4 + wpair) * 20;
        if (lane < 16)       po[lane] = pm;
        else if (lane == 16) po[16] = pre;
        else if (lane == 17) po[17] = pim;
        else if (lane == 18) po[18] = ppt;
    }

    // last block of this batch runs the readout
    __threadfence();
    __syncthreads();
    if (tid == 0) flag = atomicAdd(&counter[batch], 1);
    __syncthreads();
    if (flag != 7 || wid != 0) return;
    __threadfence();

    const int tt = lane;
    if (tt < 19) {
        float s0 = 0.0f, s1 = 0.0f, s2_ = 0.0f, s3 = 0.0f;
        const float* pb = part + (size_t)batch * 32 * 20 + tt;
        #pragma unroll
        for (int r = 0; r < 32; r += 4) {
            s0 += pb[(r + 0) * 20];
            s1 += pb[(r + 1) * 20];
            s2_ += pb[(r + 2) * 20];
            s3 += pb[(r + 3) * 20];
        }
        sbuf[tt] = (s0 + s1) + (s2_ + s3);
    }
    const float invd = __builtin_amdgcn_rcpf(sbuf[18]);   // same-wave LDS order
    if (tt < 18) xg[tt] = sbuf[tt] * invd;

    if (tt < 32) {
        float h = rb0[tt];
        #pragma unroll
        for (int k = 0; k < 16; ++k) h = fmaf(xg[k], rw0[k * 32 + tt], h);
        h = fmaxf(h, 0.01f * h);
        h1r[tt] = h;
    }
    if (tt < 32) {
        float h = rb1[tt];
        #pragma unroll
        for (int k = 0; k < 32; ++k) h = fmaf(h1r[k], rw1[k * 32 + tt], h);
        h = fmaxf(h, 0.01f * h);
        float p = h * rw2[tt];
        #pragma unroll
        for (int off = 16; off; off >>= 1) p += __shfl_xor(p, off);
        if (tt == 0) {
            out[batch * 3 + 0] = 1.0f / (1.0f + expf(-(p + rb2[0])));
            out[batch * 3 + 1] = xg[16];
            out[batch * 3 + 2] = xg[17];
        }
    }
}

extern "C" void kernel_launch(void* const* d_in, const int* in_sizes, int n_in,
                              void* d_out, int out_size, void* d_ws, size_t ws_size,
                              hipStream_t stream) {
    const float* pt    = (const float*)d_in[0];
    const float* ang   = (const float*)d_in[1];
    const float* c0_w0 = (const float*)d_in[2];
    const float* c0_b0 = (const float*)d_in[3];
    const float* c0_w1 = (const float*)d_in[4];
    const float* c0_b1 = (const float*)d_in[5];
    const float* c1_w0 = (const float*)d_in[6];
    const float* c1_b0 = (const float*)d_in[7];
    const float* c1_w1 = (const float*)d_in[8];
    const float* c1_b1 = (const float*)d_in[9];
    const float* r_w0  = (const float*)d_in[10];
    const float* r_b0  = (const float*)d_in[11];
    const float* r_w1  = (const float*)d_in[12];
    const float* r_b1  = (const float*)d_in[13];
    const float* r_w2  = (const float*)d_in[14];
    const float* r_b2  = (const float*)d_in[15];
    float* out = (float*)d_out;
    float* ws = (float*)d_ws;

    float* recb  = ws;                          // BN*4
    float* u1    = recb + (size_t)BN * 4;       // BN*16
    float* v1    = u1 + (size_t)BN * 16;        // BN*16
    float* partb = v1 + (size_t)BN * 16;        // 4096*20
    int*   cnt   = (int*)(partb + (size_t)4096 * 20);  // B ints

    hipLaunchKernelGGL(conv0_kernel, dim3(BN / 16), dim3(512), 0, stream,
                       ang, c0_w0, c0_b0, c0_w1, c0_b1, c1_w0, c1_b0,
                       recb, u1, v1, cnt);
    hipLaunchKernelGGL(conv1_kernel, dim3(BN / 16), dim3(512), 0, stream,
                       pt, recb, u1, v1, c1_w0, c1_w1, c1_b1, partb, cnt,
                       r_w0, r_b0, r_w1, r_b1, r_w2, r_b2, out);
}

// Round 8
// 41.226 us; speedup vs baseline: 4.0423x; 4.0423x over previous
//
#include <hip/hip_runtime.h>
#include <math.h>

// SMEFTNet forward. B=128, N=128, H=16.  Three kernels (R6 structure).
// Block = 16 nodes, 256 thr = 4 waves; wave owns 4 nodes, full j-range.
// lane = g*16+t: g = node subgroup 0..3, t = channel & j-sub-index.
// conv0: all 8 j-payloads (float2 ang) preloaded -> pure-compute main loop.
// conv1: 3-deep rotating register prefetch (rec float4 + v1 4xfloat4) so
// loads for j+3 are in flight while computing j. Epilogue-only data (w1
// column, proj weights) loaded after the loop to cut loop VGPR pressure.
// rec = (re, im, ex, ey) post-rotation raw + unit vectors: conv1 loop has
// no rsqrt (cos=dot(ei,ej), sin=cross(ei,ej)).

#define BB 128
#define NN 128
#define BN (BB * NN)

typedef float f32x2 __attribute__((ext_vector_type(2)));

__device__ __forceinline__ f32x2 pk2(float s) { f32x2 r; r[0] = s; r[1] = s; return r; }
__device__ __forceinline__ f32x2 pkfma(f32x2 a, f32x2 b, f32x2 c) {
    return __builtin_elementwise_fma(a, b, c);
}
__device__ __forceinline__ f32x2 pkmax(f32x2 a, f32x2 b) {
    return __builtin_elementwise_max(a, b);
}

template <int CTRL>
__device__ __forceinline__ float dpp_add(float x) {
    int tmp = __builtin_amdgcn_update_dpp(0, __float_as_int(x), CTRL, 0xF, 0xF, true);
    return x + __int_as_float(tmp);
}

// Sum within each 16-lane row; result valid in lane (l|15) of each row.
__device__ __forceinline__ float grp16_sum(float x) {
    x = dpp_add<0xB1>(x);   // quad_perm [1,0,3,2]
    x = dpp_add<0x4E>(x);   // quad_perm [2,3,0,1]
    x = dpp_add<0x114>(x);  // row_shr:4
    x = dpp_add<0x118>(x);  // row_shr:8
    return x;
}

__device__ __forceinline__ float bcast_grp(float x, int bidx) {
    return __int_as_float(__builtin_amdgcn_ds_bpermute(bidx, __float_as_int(x)));
}

__device__ __forceinline__ f32x2 grp16_red2(f32x2 x, int bidx) {
    f32x2 r;
    r[0] = bcast_grp(grp16_sum(x[0]), bidx);
    r[1] = bcast_grp(grp16_sum(x[1]), bidx);
    return r;
}

// ---------------- K1: conv0 + fused proj for conv1 ----------------
__global__ __launch_bounds__(256, 4) void conv0_kernel(
    const float* __restrict__ ang,   // (B,N,2)
    const float* __restrict__ w0,    // c0_w0 (5,16)
    const float* __restrict__ b0,    // (16)
    const float* __restrict__ w1,    // c0_w1 (16,17)
    const float* __restrict__ b1,    // (17)
    const float* __restrict__ nw0,   // c1_w0 (50,16)
    const float* __restrict__ nb0,   // c1_b0 (16)
    float* __restrict__ rec,         // (BN,4): re,im,ex,ey (post-rotation)
    float* __restrict__ u1,          // (BN,16)
    float* __restrict__ v1)          // (BN,16)
{
    const int lane = threadIdx.x & 63;
    const int wid  = threadIdx.x >> 6;
    const int t    = lane & 15;
    const int g    = lane >> 4;
    const int ni   = blockIdx.x * 16 + wid * 4 + g;
    const int base = (blockIdx.x >> 3) << 7;

    __shared__ float hls[16][20];

    // my node
    const float2 ai = ((const float2*)ang)[ni];
    const float r2i = fmaf(ai.x, ai.x, ai.y * ai.y);
    const float abszi = __builtin_amdgcn_sqrtf(r2i);
    const float ivi = fminf(__builtin_amdgcn_rsqf(r2i), 1e12f);
    const float eix = ai.x * ivi, eiy = ai.y * ivi;

    // preload all 8 j-payloads (pure-compute main loop)
    float2 ajv[8];
    #pragma unroll
    for (int jj = 0; jj < 8; ++jj)
        ajv[jj] = ((const float2*)ang)[base + jj * 16 + t];

    // layer-0 constants: uniform weights (s_load); u0b per-lane
    f32x2 u0b2[8], q02[8], wc2[8], ws2[8];
    #pragma unroll
    for (int p = 0; p < 8; ++p) {
        f32x2 wa  = *(const f32x2*)(w0 + 2 * p);
        f32x2 wb  = *(const f32x2*)(w0 + 16 + 2 * p);
        f32x2 wcv = *(const f32x2*)(w0 + 32 + 2 * p);
        f32x2 bb  = *(const f32x2*)(b0 + 2 * p);
        u0b2[p] = pkfma(pk2(abszi), wa - wcv, bb);   // absz_i*(Wa-Wc)+b0
        q02[p]  = wb + wcv;                          // Wb+Wc
        wc2[p]  = *(const f32x2*)(w0 + 48 + 2 * p);
        ws2[p]  = *(const f32x2*)(w0 + 64 + 2 * p);
    }

    f32x2 A2[8];
    #pragma unroll
    for (int p = 0; p < 8; ++p) A2[p] = pk2(0.0f);
    float degf = 0.0f;

    #pragma unroll
    for (int jj = 0; jj < 8; ++jj) {
        const float2 aj = ajv[jj];
        const float r2j = fmaf(aj.x, aj.x, aj.y * aj.y);
        const float abszj = __builtin_amdgcn_sqrtf(r2j);
        const float ivj = fminf(__builtin_amdgcn_rsqf(r2j), 1e12f);
        const float ejx = aj.x * ivj, ejy = aj.y * ivj;
        const float dre = ai.x - aj.x, dim = ai.y - aj.y;
        const float d2 = fmaf(dre, dre, dim * dim);
        const float adjf = (d2 <= 0.16f) ? 1.0f : 0.0f;
        degf += adjf;
        const f32x2 cos2 = pk2(fmaf(eix, ejx, eiy * ejy));
        const f32x2 sin2 = pk2(fmaf(eiy, ejx, -(eix * ejy)));
        const f32x2 ab2 = pk2(abszj);
        const f32x2 adj2 = pk2(adjf);
        #pragma unroll
        for (int p = 0; p < 8; ++p) {
            f32x2 z = pkfma(ab2, q02[p], u0b2[p]);
            z = pkfma(cos2, wc2[p], z);
            z = pkfma(sin2, ws2[p], z);
            f32x2 a = pkmax(z, z * 0.01f);
            A2[p] = pkfma(a, adj2, A2[p]);
        }
    }

    // reduce within 16-lane groups + broadcast
    const int bidx = (lane | 15) << 2;
    f32x2 Ak2[8];
    #pragma unroll
    for (int p = 0; p < 8; ++p) Ak2[p] = grp16_red2(A2[p], bidx);
    const float invdeg = __builtin_amdgcn_rcpf(bcast_grp(grp16_sum(degf), bidx));

    // 2nd layer (epilogue-only loads): channel t + gamma column
    f32x2 s2 = pk2(0.0f), g2 = pk2(0.0f);
    #pragma unroll
    for (int p = 0; p < 8; ++p) {
        f32x2 wr; wr[0] = w1[(2 * p) * 17 + t];  wr[1] = w1[(2 * p + 1) * 17 + t];
        f32x2 wg; wg[0] = w1[(2 * p) * 17 + 16]; wg[1] = w1[(2 * p + 1) * 17 + 16];
        s2 = pkfma(Ak2[p], wr, s2);
        g2 = pkfma(Ak2[p], wg, g2);
    }
    const float mt    = fmaf(s2[0] + s2[1], invdeg, b1[t]);
    const float gamma = fmaf(g2[0] + g2[1], invdeg, b1[16]);

    // rotation (v_cos/v_sin take revolutions); rotate raw and unit vectors
    {
        const float gf = gamma - floorf(gamma);
        const float cs = __builtin_amdgcn_cosf(gf);
        const float sn = __builtin_amdgcn_sinf(gf);
        if (t == 0) {
            const float re2 = cs * ai.x - sn * ai.y;
            const float im2 = fmaf(sn, ai.x, cs * ai.y);
            const float e1x = cs * eix - sn * eiy;
            const float e1y = fmaf(sn, eix, cs * eiy);
            ((float4*)rec)[ni] = make_float4(re2, im2, e1x, e1y);
        }
    }

    hls[wid * 4 + g][t] = mt;   // same-wave exchange (in-order, no barrier)

    // proj: 2 passes x 64 lanes = 4 nodes x (16 u + 16 v)
    const int o = lane & 31;
    const int kk = o & 15;
    const bool isU = (o < 16);
    const float accb = isU ? nb0[kk] : 0.0f;
    f32x2 wk2[8];
    {
        const int off = isU ? 0 : 256;
        const float sgn = isU ? -1.0f : 1.0f;
        #pragma unroll
        for (int p = 0; p < 8; ++p) {
            f32x2 a_; a_[0] = nw0[off + (2 * p) * 16 + kk]; a_[1] = nw0[off + (2 * p + 1) * 16 + kk];
            f32x2 c_; c_[0] = nw0[512 + (2 * p) * 16 + kk]; c_[1] = nw0[512 + (2 * p + 1) * 16 + kk];
            wk2[p] = pkfma(pk2(sgn), c_, a_);
        }
    }
    #pragma unroll
    for (int ps = 0; ps < 2; ++ps) {
        const int nl = (lane >> 5) + 2 * ps;
        const int node = wid * 4 + nl;
        const float4* hr = (const float4*)&hls[node][0];
        float4 h0 = hr[0], h1 = hr[1], h2 = hr[2], h3 = hr[3];
        f32x2 hv[8];
        hv[0][0] = h0.x; hv[0][1] = h0.y; hv[1][0] = h0.z; hv[1][1] = h0.w;
        hv[2][0] = h1.x; hv[2][1] = h1.y; hv[3][0] = h1.z; hv[3][1] = h1.w;
        hv[4][0] = h2.x; hv[4][1] = h2.y; hv[5][0] = h2.z; hv[5][1] = h2.w;
        hv[6][0] = h3.x; hv[6][1] = h3.y; hv[7][0] = h3.z; hv[7][1] = h3.w;
        f32x2 acc2 = pk2(0.0f);
        #pragma unroll
        for (int p = 0; p < 8; ++p) acc2 = pkfma(hv[p], wk2[p], acc2);
        const float acc = acc2[0] + acc2[1] + accb;
        const int nout = blockIdx.x * 16 + node;
        if (isU) u1[nout * 16 + kk] = acc;
        else     v1[nout * 16 + kk] = acc;
    }
}

// ---------------- K2: conv1 + per-wave readout partials ----------------
__global__ __launch_bounds__(256, 4) void conv1_kernel(
    const float* __restrict__ pt,    // (B,N)
    const float* __restrict__ rec,   // (BN,4)
    const float* __restrict__ u1,    // (BN,16)
    const float* __restrict__ v1,    // (BN,16)
    const float* __restrict__ w0,    // c1_w0 (50,16)
    const float* __restrict__ w1,    // c1_w1 (16,17)
    const float* __restrict__ b1,    // (17)
    float* __restrict__ part)        // (4096,20)
{
    const int lane = threadIdx.x & 63;
    const int wid  = threadIdx.x >> 6;
    const int t    = lane & 15;
    const int g    = lane >> 4;
    const int ni   = blockIdx.x * 16 + wid * 4 + g;
    const int base = (blockIdx.x >> 3) << 7;

    // my node
    const float4 r4i = ((const float4*)rec)[ni];
    const float rei = r4i.x, imi = r4i.y, eix = r4i.z, eiy = r4i.w;
    const float ptf = pt[ni];
    f32x2 u0b2[8];
    {
        const float4* ug = (const float4*)(u1 + (size_t)ni * 16);
        float4 q0 = ug[0], q1 = ug[1], q2 = ug[2], q3 = ug[3];
        u0b2[0][0] = q0.x; u0b2[0][1] = q0.y; u0b2[1][0] = q0.z; u0b2[1][1] = q0.w;
        u0b2[2][0] = q1.x; u0b2[2][1] = q1.y; u0b2[3][0] = q1.z; u0b2[3][1] = q1.w;
        u0b2[4][0] = q2.x; u0b2[4][1] = q2.y; u0b2[5][0] = q2.z; u0b2[5][1] = q2.w;
        u0b2[6][0] = q3.x; u0b2[6][1] = q3.y; u0b2[7][0] = q3.z; u0b2[7][1] = q3.w;
    }
    f32x2 wc2[8], ws2[8];   // uniform addresses -> s_load
    #pragma unroll
    for (int p = 0; p < 8; ++p) {
        wc2[p] = *(const f32x2*)(w0 + 768 + 2 * p);
        ws2[p] = *(const f32x2*)(w0 + 784 + 2 * p);
    }

    f32x2 A2[8];
    #pragma unroll
    for (int p = 0; p < 8; ++p) A2[p] = pk2(0.0f);
    float degf = 0.0f;

    // 3-deep rotating register prefetch
    float4 pa[3], pv0[3], pv1[3], pv2[3], pv3[3];
#define LJ(slot, jj) { const int j_ = base + (jj) * 16 + t;                     \
        pa[slot] = ((const float4*)rec)[j_];                                    \
        const float4* vg_ = (const float4*)(v1 + (size_t)j_ * 16);              \
        pv0[slot] = vg_[0]; pv1[slot] = vg_[1];                                 \
        pv2[slot] = vg_[2]; pv3[slot] = vg_[3]; }
#define STEP(jj, slot, pf)                                                      \
    {   const float4 r4 = pa[slot];                                             \
        const float4 q0 = pv0[slot], q1 = pv1[slot], q2 = pv2[slot], q3 = pv3[slot]; \
        if (pf) LJ(slot, (jj) + 3);                                             \
        f32x2 vj2[8];                                                           \
        vj2[0][0] = q0.x; vj2[0][1] = q0.y; vj2[1][0] = q0.z; vj2[1][1] = q0.w; \
        vj2[2][0] = q1.x; vj2[2][1] = q1.y; vj2[3][0] = q1.z; vj2[3][1] = q1.w; \
        vj2[4][0] = q2.x; vj2[4][1] = q2.y; vj2[5][0] = q2.z; vj2[5][1] = q2.w; \
        vj2[6][0] = q3.x; vj2[6][1] = q3.y; vj2[7][0] = q3.z; vj2[7][1] = q3.w; \
        const float dre = rei - r4.x, dim = imi - r4.y;                         \
        const float d2 = fmaf(dre, dre, dim * dim);                             \
        const float adjf = (d2 <= 0.16f) ? 1.0f : 0.0f;                         \
        degf += adjf;                                                           \
        const f32x2 cos2 = pk2(fmaf(eix, r4.z, eiy * r4.w));                    \
        const f32x2 sin2 = pk2(fmaf(eiy, r4.z, -(eix * r4.w)));                 \
        const f32x2 adj2 = pk2(adjf);                                           \
        _Pragma("unroll")                                                       \
        for (int p = 0; p < 8; ++p) {                                           \
            f32x2 z = u0b2[p] + vj2[p];                                         \
            z = pkfma(cos2, wc2[p], z);                                         \
            z = pkfma(sin2, ws2[p], z);                                         \
            f32x2 a = pkmax(z, z * 0.01f);                                      \
            A2[p] = pkfma(a, adj2, A2[p]);                                      \
        }                                                                       \
    }

    LJ(0, 0); LJ(1, 1); LJ(2, 2);
    STEP(0, 0, 1); STEP(1, 1, 1); STEP(2, 2, 1); STEP(3, 0, 1); STEP(4, 1, 1);
    STEP(5, 2, 0); STEP(6, 0, 0); STEP(7, 1, 0);
#undef STEP
#undef LJ

    const int bidx = (lane | 15) << 2;
    f32x2 Ak2[8];
    #pragma unroll
    for (int p = 0; p < 8; ++p) Ak2[p] = grp16_red2(A2[p], bidx);
    const float invdeg = __builtin_amdgcn_rcpf(bcast_grp(grp16_sum(degf), bidx));

    // 2nd layer (epilogue-only loads)
    f32x2 s2 = pk2(0.0f), g2 = pk2(0.0f);
    #pragma unroll
    for (int p = 0; p < 8; ++p) {
        f32x2 wr; wr[0] = w1[(2 * p) * 17 + t];  wr[1] = w1[(2 * p + 1) * 17 + t];
        f32x2 wg; wg[0] = w1[(2 * p) * 17 + 16]; wg[1] = w1[(2 * p + 1) * 17 + 16];
        s2 = pkfma(Ak2[p], wr, s2);
        g2 = pkfma(Ak2[p], wg, g2);
    }
    const float mt    = fmaf(s2[0] + s2[1], invdeg, b1[t]);
    const float gamma = fmaf(g2[0] + g2[1], invdeg, b1[16]);

    const float gf = gamma - floorf(gamma);
    const float cs = __builtin_amdgcn_cosf(gf);
    const float sn = __builtin_amdgcn_sinf(gf);
    const float re2 = cs * rei - sn * imi;
    const float im2 = fmaf(sn, rei, cs * imi);

    // per-wave partials over its 4 nodes: xor16 (swizzle) + xor32 (shfl)
    float pm  = ptf * mt;
    float pre = ptf * re2;
    float pim = ptf * im2;
    float ppt = ptf;
    pm  += __int_as_float(__builtin_amdgcn_ds_swizzle(__float_as_int(pm),  0x401F));
    pre += __int_as_float(__builtin_amdgcn_ds_swizzle(__float_as_int(pre), 0x401F));
    pim += __int_as_float(__builtin_amdgcn_ds_swizzle(__float_as_int(pim), 0x401F));
    ppt += __int_as_float(__builtin_amdgcn_ds_swizzle(__float_as_int(ppt), 0x401F));
    pm  += __shfl_xor(pm, 32);
    pre += __shfl_xor(pre, 32);
    pim += __shfl_xor(pim, 32);
    ppt += __shfl_xor(ppt, 32);

    float* po = part + (size_t)(blockIdx.x * 4 + wid) * 20;
    if (lane < 16)       po[lane] = pm;
    else if (lane == 16) po[16] = pre;
    else if (lane == 17) po[17] = pim;
    else if (lane == 18) po[18] = ppt;
}

// ---------------- K3: final readout (1 wave per batch) ----------------
__global__ __launch_bounds__(64) void readout_kernel(
    const float* __restrict__ part,  // (4096,20)
    const float* __restrict__ w0, const float* __restrict__ b0,  // (16,32),(32)
    const float* __restrict__ w1, const float* __restrict__ b1,  // (32,32),(32)
    const float* __restrict__ w2, const float* __restrict__ b2,  // (32,1),(1)
    float* __restrict__ out) {
    const int b = blockIdx.x;
    const int t = threadIdx.x;

    __shared__ float sbuf[19];
    __shared__ float xg[18];
    __shared__ float h1r[32];

    if (t < 19) {
        float s0 = 0.0f, s1 = 0.0f, s2 = 0.0f, s3 = 0.0f;
        const float* pb = part + (size_t)b * 32 * 20 + t;
        #pragma unroll
        for (int r = 0; r < 32; r += 4) {
            s0 += pb[(r + 0) * 20];
            s1 += pb[(r + 1) * 20];
            s2 += pb[(r + 2) * 20];
            s3 += pb[(r + 3) * 20];
        }
        sbuf[t] = (s0 + s1) + (s2 + s3);
    }
    // same wave: LDS ops in-order, no barrier needed
    const float invd = __builtin_amdgcn_rcpf(sbuf[18]);
    if (t < 18) xg[t] = sbuf[t] * invd;

    if (t < 32) {
        float h = b0[t];
        #pragma unroll
        for (int k = 0; k < 16; ++k) h = fmaf(xg[k], w0[k * 32 + t], h);
        h = fmaxf(h, 0.01f * h);
        h1r[t] = h;
    }
    if (t < 32) {
        float h = b1[t];
        #pragma unroll
        for (int k = 0; k < 32; ++k) h = fmaf(h1r[k], w1[k * 32 + t], h);
        h = fmaxf(h, 0.01f * h);
        float p = h * w2[t];
        #pragma unroll
        for (int off = 16; off; off >>= 1) p += __shfl_xor(p, off);
        if (t == 0) {
            out[b * 3 + 0] = 1.0f / (1.0f + expf(-(p + b2[0])));
            out[b * 3 + 1] = xg[16];
            out[b * 3 + 2] = xg[17];
        }
    }
}

extern "C" void kernel_launch(void* const* d_in, const int* in_sizes, int n_in,
                              void* d_out, int out_size, void* d_ws, size_t ws_size,
                              hipStream_t stream) {
    const float* pt    = (const float*)d_in[0];
    const float* ang   = (const float*)d_in[1];
    const float* c0_w0 = (const float*)d_in[2];
    const float* c0_b0 = (const float*)d_in[3];
    const float* c0_w1 = (const float*)d_in[4];
    const float* c0_b1 = (const float*)d_in[5];
    const float* c1_w0 = (const float*)d_in[6];
    const float* c1_b0 = (const float*)d_in[7];
    const float* c1_w1 = (const float*)d_in[8];
    const float* c1_b1 = (const float*)d_in[9];
    const float* r_w0  = (const float*)d_in[10];
    const float* r_b0  = (const float*)d_in[11];
    const float* r_w1  = (const float*)d_in[12];
    const float* r_b1  = (const float*)d_in[13];
    const float* r_w2  = (const float*)d_in[14];
    const float* r_b2  = (const float*)d_in[15];
    float* out = (float*)d_out;
    float* ws = (float*)d_ws;

    float* recb  = ws;                          // BN*4
    float* u1    = recb + (size_t)BN * 4;       // BN*16
    float* v1    = u1 + (size_t)BN * 16;        // BN*16
    float* partb = v1 + (size_t)BN * 16;        // 4096*20

    hipLaunchKernelGGL(conv0_kernel, dim3(BN / 16), dim3(256), 0, stream,
                       ang, c0_w0, c0_b0, c0_w1, c0_b1, c1_w0, c1_b0,
                       recb, u1, v1);
    hipLaunchKernelGGL(conv1_kernel, dim3(BN / 16), dim3(256), 0, stream,
                       pt, recb, u1, v1, c1_w0, c1_w1, c1_b1, partb);
    hipLaunchKernelGGL(readout_kernel, dim3(BB), dim3(64), 0, stream,
                       partb, r_w0, r_b0, r_w1, r_b1, r_w2, r_b2, out);
}

// Round 9
// 33.204 us; speedup vs baseline: 5.0190x; 1.2416x over previous
//
#include <hip/hip_runtime.h>
#include <math.h>

// SMEFTNet forward. B=128, N=128, H=16.  R6 "Config Y" base (30.2us) + load-
// batching tweaks. 4 nodes per wave; lane = g*16+t (g node subgroup, t chan).
// conv0: all 8 j-payloads preloaded -> pure-compute loop.
// conv1: full unroll (compiler hoists the 40 j-loads); w1 column loads moved
// to the epilogue to cut loop-live VGPRs. launch_bounds(256,4) caps VGPR=128.

#define BB 128
#define NN 128
#define BN (BB * NN)

typedef float f32x2 __attribute__((ext_vector_type(2)));

__device__ __forceinline__ f32x2 pk2(float s) { f32x2 r; r[0] = s; r[1] = s; return r; }
__device__ __forceinline__ f32x2 pkfma(f32x2 a, f32x2 b, f32x2 c) {
    return __builtin_elementwise_fma(a, b, c);
}
__device__ __forceinline__ f32x2 pkmax(f32x2 a, f32x2 b) {
    return __builtin_elementwise_max(a, b);
}

template <int CTRL>
__device__ __forceinline__ float dpp_add(float x) {
    int tmp = __builtin_amdgcn_update_dpp(0, __float_as_int(x), CTRL, 0xF, 0xF, true);
    return x + __int_as_float(tmp);
}

// Sum within each 16-lane row; result valid in lane (l|15) of each row.
__device__ __forceinline__ float grp16_sum(float x) {
    x = dpp_add<0xB1>(x);   // quad_perm [1,0,3,2]
    x = dpp_add<0x4E>(x);   // quad_perm [2,3,0,1]
    x = dpp_add<0x114>(x);  // row_shr:4
    x = dpp_add<0x118>(x);  // row_shr:8
    return x;
}

__device__ __forceinline__ float bcast_grp(float x, int bidx) {
    return __int_as_float(__builtin_amdgcn_ds_bpermute(bidx, __float_as_int(x)));
}

__device__ __forceinline__ f32x2 grp16_red2(f32x2 x, int bidx) {
    f32x2 r;
    r[0] = bcast_grp(grp16_sum(x[0]), bidx);
    r[1] = bcast_grp(grp16_sum(x[1]), bidx);
    return r;
}

// ---------------- K1: conv0 + fused proj for conv1 ----------------
__global__ __launch_bounds__(256, 4) void conv0_kernel(
    const float* __restrict__ ang,   // (B,N,2)
    const float* __restrict__ w0,    // c0_w0 (5,16)
    const float* __restrict__ b0,    // (16)
    const float* __restrict__ w1,    // c0_w1 (16,17)
    const float* __restrict__ b1,    // (17)
    const float* __restrict__ nw0,   // c1_w0 (50,16)
    const float* __restrict__ nb0,   // c1_b0 (16)
    float* __restrict__ ang1,        // (BN,4): re,im,inv,0
    float* __restrict__ u1,          // (BN,16)
    float* __restrict__ v1)          // (BN,16)
{
    const int tid  = threadIdx.x;
    const int lane = tid & 63;
    const int wid  = tid >> 6;
    const int t    = lane & 15;      // channel / j-sub-index
    const int g    = lane >> 4;      // node subgroup 0..3
    const int ni   = blockIdx.x * 16 + wid * 4 + g;
    const int base = (blockIdx.x >> 3) << 7;   // batch start node

    __shared__ float hls[16][20];

    // my node
    const float2 ai = ((const float2*)ang)[ni];
    const float r2i = fmaf(ai.x, ai.x, ai.y * ai.y);
    const float abszi = __builtin_amdgcn_sqrtf(r2i);
    const float invi  = __builtin_amdgcn_rsqf(r2i);

    // preload all 8 j payloads (pure-compute main loop)
    float2 ajv[8];
    #pragma unroll
    for (int jj = 0; jj < 8; ++jj)
        ajv[jj] = ((const float2*)ang)[base + jj * 16 + t];

    // layer-0 row constants (wave-uniform -> s_load) + per-lane u0b
    f32x2 u0b2[8], q02[8], wc2[8], ws2[8];
    #pragma unroll
    for (int p = 0; p < 8; ++p) {
        f32x2 wa  = *(const f32x2*)(w0 + 2 * p);
        f32x2 wb  = *(const f32x2*)(w0 + 16 + 2 * p);
        f32x2 wcv = *(const f32x2*)(w0 + 32 + 2 * p);
        f32x2 bb  = *(const f32x2*)(b0 + 2 * p);
        u0b2[p] = pkfma(pk2(abszi), wa - wcv, bb);   // absz_i*(Wa-Wc)+b0
        q02[p]  = wb + wcv;                          // Wb+Wc
        wc2[p]  = *(const f32x2*)(w0 + 48 + 2 * p);
        ws2[p]  = *(const f32x2*)(w0 + 64 + 2 * p);
    }

    // prefetch w1 column t (per-lane) and gamma column (uniform)
    float w1row[16], w1g[16];
    #pragma unroll
    for (int k = 0; k < 16; ++k) {
        w1row[k] = w1[k * 17 + t];
        w1g[k]   = w1[k * 17 + 16];
    }
    const float b1t = b1[t], b1g = b1[16];

    // prefetch + combine proj weights: output o = lane&31 (k = o&15, u/v half)
    const int o   = lane & 31;
    const int kk  = o & 15;
    const bool isU = (o < 16);
    float wk[16];
    {
        const int off = isU ? 0 : 256;
        #pragma unroll
        for (int c = 0; c < 16; ++c) {
            float a_ = nw0[off + c * 16 + kk];
            float c_ = nw0[512 + c * 16 + kk];
            wk[c] = isU ? (a_ - c_) : (a_ + c_);
        }
    }
    const float accb = isU ? nb0[kk] : 0.0f;

    // j-loop: 8 iters, j = 16*jj + t
    f32x2 A2[8];
    #pragma unroll
    for (int p = 0; p < 8; ++p) A2[p] = pk2(0.0f);
    float degf = 0.0f;

    #pragma unroll
    for (int jj = 0; jj < 8; ++jj) {
        const float2 aj = ajv[jj];
        const float r2j = fmaf(aj.x, aj.x, aj.y * aj.y);
        const float abszj = __builtin_amdgcn_sqrtf(r2j);
        const float ivj   = __builtin_amdgcn_rsqf(r2j);
        const float dre = ai.x - aj.x, dim = ai.y - aj.y;
        const float d2 = fmaf(dre, dre, dim * dim);
        const float adjf = (d2 <= 0.16f) ? 1.0f : 0.0f;
        degf += adjf;
        const float inv = fminf(invi * ivj, 1e12f);
        const f32x2 cos2 = pk2(fmaf(ai.x, aj.x, ai.y * aj.y) * inv);
        const f32x2 sin2 = pk2(fmaf(ai.y, aj.x, -(ai.x * aj.y)) * inv);
        const f32x2 ab2 = pk2(abszj);
        const f32x2 adj2 = pk2(adjf);
        #pragma unroll
        for (int p = 0; p < 8; ++p) {
            f32x2 z = pkfma(ab2, q02[p], u0b2[p]);
            z = pkfma(cos2, wc2[p], z);
            z = pkfma(sin2, ws2[p], z);
            f32x2 a = pkmax(z, z * 0.01f);
            A2[p] = pkfma(a, adj2, A2[p]);
        }
    }

    // reduce: 17 chains, 4-step DPP + bpermute broadcast from lane (l|15)
    const int bidx = (lane | 15) << 2;
    f32x2 Ak2[8];
    #pragma unroll
    for (int p = 0; p < 8; ++p) Ak2[p] = grp16_red2(A2[p], bidx);
    const float invdeg = __builtin_amdgcn_rcpf(bcast_grp(grp16_sum(degf), bidx));

    // 2nd MLP layer: channel t (per-lane weights) + gamma (SGPR weights)
    f32x2 s2 = pk2(0.0f), g2 = pk2(0.0f);
    #pragma unroll
    for (int p = 0; p < 8; ++p) {
        f32x2 wr; wr[0] = w1row[2 * p]; wr[1] = w1row[2 * p + 1];
        f32x2 wg; wg[0] = w1g[2 * p];   wg[1] = w1g[2 * p + 1];
        s2 = pkfma(Ak2[p], wr, s2);
        g2 = pkfma(Ak2[p], wg, g2);
    }
    const float mt    = fmaf(s2[0] + s2[1], invdeg, b1t);
    const float gamma = fmaf(g2[0] + g2[1], invdeg, b1g);

    // rotation (v_cos/v_sin take revolutions); norm preserved -> store invi
    {
        const float gf = gamma - floorf(gamma);
        const float cs = __builtin_amdgcn_cosf(gf);
        const float sn = __builtin_amdgcn_sinf(gf);
        const float re2 = cs * ai.x - sn * ai.y;
        const float im2 = fmaf(sn, ai.x, cs * ai.y);
        if (t == 0) ((float4*)ang1)[ni] = make_float4(re2, im2, invi, 0.0f);
    }

    // h-exchange (same-wave LDS, no barrier needed)
    hls[wid * 4 + g][t] = mt;

    // proj: 2 passes x 64 lanes = 128 outputs (4 nodes x (16 u + 16 v))
    #pragma unroll
    for (int p = 0; p < 2; ++p) {
        const int nl = (lane >> 5) + 2 * p;       // node local 0..3
        const int node = wid * 4 + nl;
        float acc = accb;
        #pragma unroll
        for (int c = 0; c < 16; ++c) acc = fmaf(hls[node][c], wk[c], acc);
        const int nout = (blockIdx.x * 16 + node);
        if (isU) u1[nout * 16 + kk] = acc;
        else     v1[nout * 16 + kk] = acc;
    }
}

// ---------------- K2: conv1 + per-wave readout partials ----------------
__global__ __launch_bounds__(256, 4) void conv1_kernel(
    const float* __restrict__ pt,    // (B,N)
    const float* __restrict__ ang1,  // (BN,4): re,im,inv,0
    const float* __restrict__ u1,    // (BN,16)
    const float* __restrict__ v1,    // (BN,16)
    const float* __restrict__ w0,    // c1_w0 (50,16)
    const float* __restrict__ w1,    // c1_w1 (16,17)
    const float* __restrict__ b1,    // (17)
    float* __restrict__ part)        // (4096,20): [0..15]=sum pt*m, 16=re,17=im,18=sum pt
{
    const int tid  = threadIdx.x;
    const int lane = tid & 63;
    const int wid  = tid >> 6;
    const int t    = lane & 15;
    const int g    = lane >> 4;
    const int ni   = blockIdx.x * 16 + wid * 4 + g;
    const int base = (blockIdx.x >> 3) << 7;

    // my node
    const float4 a4 = ((const float4*)ang1)[ni];
    const float rei = a4.x, imi = a4.y, invi = a4.z;
    const float ptf = pt[ni];

    f32x2 u0b2[8], wc2[8], ws2[8];
    {
        const float4* ug = (const float4*)(u1 + (size_t)ni * 16);
        float4 q0 = ug[0], q1 = ug[1], q2 = ug[2], q3 = ug[3];
        u0b2[0][0] = q0.x; u0b2[0][1] = q0.y; u0b2[1][0] = q0.z; u0b2[1][1] = q0.w;
        u0b2[2][0] = q1.x; u0b2[2][1] = q1.y; u0b2[3][0] = q1.z; u0b2[3][1] = q1.w;
        u0b2[4][0] = q2.x; u0b2[4][1] = q2.y; u0b2[5][0] = q2.z; u0b2[5][1] = q2.w;
        u0b2[6][0] = q3.x; u0b2[6][1] = q3.y; u0b2[7][0] = q3.z; u0b2[7][1] = q3.w;
    }
    #pragma unroll
    for (int p = 0; p < 8; ++p) {
        wc2[p] = *(const f32x2*)(w0 + 768 + 2 * p);
        ws2[p] = *(const f32x2*)(w0 + 784 + 2 * p);
    }

    f32x2 A2[8];
    #pragma unroll
    for (int p = 0; p < 8; ++p) A2[p] = pk2(0.0f);
    float degf = 0.0f;

    #pragma unroll
    for (int jj = 0; jj < 8; ++jj) {
        const int j = base + jj * 16 + t;
        const float4 aj = ((const float4*)ang1)[j];
        f32x2 vj2[8];
        {
            const float4* vg = (const float4*)(v1 + (size_t)j * 16);
            float4 q0 = vg[0], q1 = vg[1], q2 = vg[2], q3 = vg[3];
            vj2[0][0] = q0.x; vj2[0][1] = q0.y; vj2[1][0] = q0.z; vj2[1][1] = q0.w;
            vj2[2][0] = q1.x; vj2[2][1] = q1.y; vj2[3][0] = q1.z; vj2[3][1] = q1.w;
            vj2[4][0] = q2.x; vj2[4][1] = q2.y; vj2[5][0] = q2.z; vj2[5][1] = q2.w;
            vj2[6][0] = q3.x; vj2[6][1] = q3.y; vj2[7][0] = q3.z; vj2[7][1] = q3.w;
        }
        const float dre = rei - aj.x, dim = imi - aj.y;
        const float d2 = fmaf(dre, dre, dim * dim);
        const float adjf = (d2 <= 0.16f) ? 1.0f : 0.0f;
        degf += adjf;
        const float inv = fminf(invi * aj.z, 1e12f);
        const f32x2 cos2 = pk2(fmaf(rei, aj.x, imi * aj.y) * inv);
        const f32x2 sin2 = pk2(fmaf(imi, aj.x, -(rei * aj.y)) * inv);
        const f32x2 adj2 = pk2(adjf);
        #pragma unroll
        for (int p = 0; p < 8; ++p) {
            f32x2 z = u0b2[p] + vj2[p];
            z = pkfma(cos2, wc2[p], z);
            z = pkfma(sin2, ws2[p], z);
            f32x2 a = pkmax(z, z * 0.01f);
            A2[p] = pkfma(a, adj2, A2[p]);
        }
    }

    const int bidx = (lane | 15) << 2;
    f32x2 Ak2[8];
    #pragma unroll
    for (int p = 0; p < 8; ++p) Ak2[p] = grp16_red2(A2[p], bidx);
    const float invdeg = __builtin_amdgcn_rcpf(bcast_grp(grp16_sum(degf), bidx));

    // 2nd MLP layer (epilogue-only loads)
    f32x2 s2 = pk2(0.0f), g2 = pk2(0.0f);
    #pragma unroll
    for (int p = 0; p < 8; ++p) {
        f32x2 wr; wr[0] = w1[(2 * p) * 17 + t];  wr[1] = w1[(2 * p + 1) * 17 + t];
        f32x2 wg; wg[0] = w1[(2 * p) * 17 + 16]; wg[1] = w1[(2 * p + 1) * 17 + 16];
        s2 = pkfma(Ak2[p], wr, s2);
        g2 = pkfma(Ak2[p], wg, g2);
    }
    const float mt    = fmaf(s2[0] + s2[1], invdeg, b1[t]);
    const float gamma = fmaf(g2[0] + g2[1], invdeg, b1[16]);

    const float gf = gamma - floorf(gamma);
    const float cs = __builtin_amdgcn_cosf(gf);
    const float sn = __builtin_amdgcn_sinf(gf);
    const float re2 = cs * rei - sn * imi;
    const float im2 = fmaf(sn, rei, cs * imi);

    // per-wave readout partials: sum over the wave's 4 nodes.
    float pm  = ptf * mt;     // per-channel t
    float pre = ptf * re2;    // uniform within group
    float pim = ptf * im2;
    float ppt = ptf;
    // cross-group sum: xor16 (ds_swizzle) + xor32 (shfl)
    pm  += __int_as_float(__builtin_amdgcn_ds_swizzle(__float_as_int(pm),  0x401F));
    pre += __int_as_float(__builtin_amdgcn_ds_swizzle(__float_as_int(pre), 0x401F));
    pim += __int_as_float(__builtin_amdgcn_ds_swizzle(__float_as_int(pim), 0x401F));
    ppt += __int_as_float(__builtin_amdgcn_ds_swizzle(__float_as_int(ppt), 0x401F));
    pm  += __shfl_xor(pm, 32);
    pre += __shfl_xor(pre, 32);
    pim += __shfl_xor(pim, 32);
    ppt += __shfl_xor(ppt, 32);

    float* po = part + (size_t)(blockIdx.x * 4 + wid) * 20;
    if (lane < 16)       po[lane] = pm;
    else if (lane == 16) po[16] = pre;
    else if (lane == 17) po[17] = pim;
    else if (lane == 18) po[18] = ppt;
}

// ---------------- K3: final readout (1 wave per batch) ----------------
__global__ __launch_bounds__(64) void readout_kernel(
    const float* __restrict__ part,  // (4096,20)
    const float* __restrict__ w0, const float* __restrict__ b0,  // (16,32),(32)
    const float* __restrict__ w1, const float* __restrict__ b1,  // (32,32),(32)
    const float* __restrict__ w2, const float* __restrict__ b2,  // (32,1),(1)
    float* __restrict__ out) {
    const int b = blockIdx.x;
    const int t = threadIdx.x;

    __shared__ float sbuf[19];
    __shared__ float xg[18];
    __shared__ float h1r[32];

    if (t < 19) {
        float s0 = 0.0f, s1 = 0.0f, s2 = 0.0f, s3 = 0.0f;
        const float* pb = part + (size_t)b * 32 * 20 + t;
        #pragma unroll
        for (int r = 0; r < 32; r += 4) {
            s0 += pb[(r + 0) * 20];
            s1 += pb[(r + 1) * 20];
            s2 += pb[(r + 2) * 20];
            s3 += pb[(r + 3) * 20];
        }
        sbuf[t] = (s0 + s1) + (s2 + s3);
    }
    // same wave: LDS ops are in-order, no barrier needed
    const float invd = __builtin_amdgcn_rcpf(sbuf[18]);
    if (t < 18) xg[t] = sbuf[t] * invd;

    if (t < 32) {
        float h = b0[t];
        #pragma unroll
        for (int k = 0; k < 16; ++k) h = fmaf(xg[k], w0[k * 32 + t], h);
        h = fmaxf(h, 0.01f * h);
        h1r[t] = h;
    }
    if (t < 32) {
        float h = b1[t];
        #pragma unroll
        for (int k = 0; k < 32; ++k) h = fmaf(h1r[k], w1[k * 32 + t], h);
        h = fmaxf(h, 0.01f * h);
        float p = h * w2[t];
        #pragma unroll
        for (int off = 16; off; off >>= 1) p += __shfl_xor(p, off);
        if (t == 0) {
            out[b * 3 + 0] = 1.0f / (1.0f + expf(-(p + b2[0])));
            out[b * 3 + 1] = xg[16];
            out[b * 3 + 2] = xg[17];
        }
    }
}

extern "C" void kernel_launch(void* const* d_in, const int* in_sizes, int n_in,
                              void* d_out, int out_size, void* d_ws, size_t ws_size,
                              hipStream_t stream) {
    const float* pt    = (const float*)d_in[0];
    const float* ang   = (const float*)d_in[1];
    const float* c0_w0 = (const float*)d_in[2];
    const float* c0_b0 = (const float*)d_in[3];
    const float* c0_w1 = (const float*)d_in[4];
    const float* c0_b1 = (const float*)d_in[5];
    const float* c1_w0 = (const float*)d_in[6];
    const float* c1_b0 = (const float*)d_in[7];
    const float* c1_w1 = (const float*)d_in[8];
    const float* c1_b1 = (const float*)d_in[9];
    const float* r_w0  = (const float*)d_in[10];
    const float* r_b0  = (const float*)d_in[11];
    const float* r_w1  = (const float*)d_in[12];
    const float* r_b1  = (const float*)d_in[13];
    const float* r_w2  = (const float*)d_in[14];
    const float* r_b2  = (const float*)d_in[15];
    float* out = (float*)d_out;
    float* ws = (float*)d_ws;

    float* ang1  = ws;                         // BN*4
    float* u1    = ang1 + (size_t)BN * 4;      // BN*16
    float* v1    = u1 + (size_t)BN * 16;       // BN*16
    float* partb = v1 + (size_t)BN * 16;       // 4096*20

    hipLaunchKernelGGL(conv0_kernel, dim3(BN / 16), dim3(256), 0, stream,
                       ang, c0_w0, c0_b0, c0_w1, c0_b1, c1_w0, c1_b0,
                       ang1, u1, v1);
    hipLaunchKernelGGL(conv1_kernel, dim3(BN / 16), dim3(256), 0, stream,
                       pt, ang1, u1, v1, c1_w0, c1_w1, c1_b1, partb);
    hipLaunchKernelGGL(readout_kernel, dim3(BB), dim3(64), 0, stream,
                       partb, r_w0, r_b0, r_w1, r_b1, r_w2, r_b2, out);
}